// Round 8
// baseline (104.181 us; speedup 1.0000x reference)
//
#include <hip/hip_runtime.h>
#include <math.h>

#define BB 4
#define SS 256
#define DD 768
#define DEPC 100
#define HH 12

#define GLDS(gp, lp)                                                        \
    __builtin_amdgcn_global_load_lds(                                       \
        (const __attribute__((address_space(1))) void*)(gp),                \
        (__attribute__((address_space(3))) void*)(lp), 16, 0, 0)

// ---------- K1: u_t[h][p] = sum_d W_e[p][h*64+d] * w_rel[d]  (transposed) ----------
__global__ __launch_bounds__(256) void k_u(const float* __restrict__ W_e,
                                           const float* __restrict__ w_rel,
                                           float* __restrict__ u_t) {
    int e = blockIdx.x * 256 + threadIdx.x;
    if (e >= DEPC * HH) return;
    int p = e / HH, h = e % HH;
    const float4* we = (const float4*)(W_e + p * DD + h * 64);
    const float4* wr = (const float4*)w_rel;
    float acc = 0.f;
#pragma unroll
    for (int c = 0; c < 16; ++c) {
        float4 a = we[c], b = wr[c];
        acc += a.x * b.x + a.y * b.y + a.z * b.z + a.w * b.w;
    }
    u_t[h * DEPC + p] = acc;
}

// ---------- K2: V = token @ W_v.  TKK=32, b64 A-reads, reg-prefetch dbuf ----------
#define TM 32
#define TN 64
#define TKK 32
__global__ __launch_bounds__(256) void k_v(const float* __restrict__ A,
                                           const float* __restrict__ Bm,
                                           float* __restrict__ C) {
    __shared__ float As[TKK][TM + 1];  // [k][row], pad kills write conflicts
    __shared__ float Bs[TKK][TN];
    int t = threadIdx.x;
    int tx = t & 15, ty = t >> 4;      // micro: rows 2ty..2ty+1, cols 4tx..4tx+3
    int ar = t >> 3, ac4 = t & 7;      // A stage: row, k-quad
    int bk = t >> 4, bn4 = t & 15;     // B stage: k, n-quad
    int r0 = blockIdx.x * TM, c0 = blockIdx.y * TN;
    float acc[2][4] = {};

    // stage k0 = 0
    {
        float4 av = *(const float4*)&A[(r0 + ar) * DD + 4 * ac4];
#pragma unroll
        for (int m = 0; m < 4; ++m) As[4 * ac4 + m][ar] = ((const float*)&av)[m];
#pragma unroll
        for (int q = 0; q < 2; ++q) {
            int k = bk + 16 * q;
            *(float4*)&Bs[k][4 * bn4] = *(const float4*)&Bm[k * DD + c0 + 4 * bn4];
        }
    }
    __syncthreads();

    for (int k0 = 0; k0 < DD; k0 += TKK) {
        float4 an = {0, 0, 0, 0}, bn[2] = {{0, 0, 0, 0}, {0, 0, 0, 0}};
        if (k0 + TKK < DD) {
            int kn = k0 + TKK;
            an = *(const float4*)&A[(r0 + ar) * DD + kn + 4 * ac4];
#pragma unroll
            for (int q = 0; q < 2; ++q)
                bn[q] = *(const float4*)&Bm[(kn + bk + 16 * q) * DD + c0 + 4 * bn4];
        }
#pragma unroll
        for (int kk = 0; kk < TKK; ++kk) {
            float2 a = *(const float2*)&As[kk][2 * ty];
            float4 b = *(const float4*)&Bs[kk][4 * tx];
            acc[0][0] += a.x * b.x; acc[0][1] += a.x * b.y;
            acc[0][2] += a.x * b.z; acc[0][3] += a.x * b.w;
            acc[1][0] += a.y * b.x; acc[1][1] += a.y * b.y;
            acc[1][2] += a.y * b.z; acc[1][3] += a.y * b.w;
        }
        __syncthreads();
        if (k0 + TKK < DD) {
#pragma unroll
            for (int m = 0; m < 4; ++m) As[4 * ac4 + m][ar] = ((const float*)&an)[m];
#pragma unroll
            for (int q = 0; q < 2; ++q) *(float4*)&Bs[bk + 16 * q][4 * bn4] = bn[q];
        }
        __syncthreads();
    }
#pragma unroll
    for (int m = 0; m < 2; ++m) {
        float4 v = make_float4(acc[m][0], acc[m][1], acc[m][2], acc[m][3]);
        *(float4*)&C[(size_t)(r0 + 2 * ty + m) * DD + c0 + 4 * tx] = v;
    }
}

// ---------- K3: scores — 3-buffer pipeline, counted vmcnt (never 0 mid-loop) ----------
// Per wave per chunk: 6-7 global_load_lds + 3 score stores. Wait budget at top of
// iter c: newest-allowed = {c0: 6 (chunk1 loads), c1/c2: 9 (3 stores + 6 loads),
// c3: 3 (stores only)} -> all older (= chunk c's loads) complete. s_barrier makes
// that hold across waves.
__global__ __launch_bounds__(256) void k_sc(const float* __restrict__ edge,
                                            const int* __restrict__ mask,
                                            const float* __restrict__ ut,
                                            float* __restrict__ scores) {
    __shared__ float buf[3][64 * DEPC];  // 76.8 KB
    int t = threadIdx.x;
    int i = blockIdx.x, b = blockIdx.y;
    int lane = t & 63, w = t >> 6;
    const float* src = edge + (size_t)(b * SS + i) * SS * DEPC;
    const int* mrow = mask + (size_t)(b * SS + i) * SS;

    // mask values first (retire early; straight-line code => exact waitcnt tracking)
    int mk[4];
#pragma unroll
    for (int c = 0; c < 4; ++c) mk[c] = mrow[c * 64 + lane];

    // prologue: stage chunks 0,1
    for (int call = w; call < 25; call += 4)
        GLDS(src + call * 256 + lane * 4, &buf[0][call * 256]);
    for (int call = w; call < 25; call += 4)
        GLDS(src + 6400 + call * 256 + lane * 4, &buf[1][call * 256]);

    int hbase = __builtin_amdgcn_readfirstlane(w * 3);
    const float* uw = ut + hbase * DEPC;

#pragma unroll
    for (int c = 0; c < 4; ++c) {
        if (c == 0)      asm volatile("s_waitcnt vmcnt(6)" ::: "memory");
        else if (c == 3) asm volatile("s_waitcnt vmcnt(3)" ::: "memory");
        else             asm volatile("s_waitcnt vmcnt(9)" ::: "memory");
        __builtin_amdgcn_s_barrier();
        __builtin_amdgcn_sched_barrier(0);

        if (c + 2 < 4) {
            const float* s2 = src + (c + 2) * 6400;
            for (int call = w; call < 25; call += 4)
                GLDS(s2 + call * 256 + lane * 4, &buf[(c + 2) % 3][call * 256]);
        }

        const float4* row4 = (const float4*)(&buf[c % 3][lane * DEPC]);
        float4 A0 = {0, 0, 0, 0}, A1 = {0, 0, 0, 0}, A2 = {0, 0, 0, 0};
#pragma unroll
        for (int ph = 0; ph < 5; ++ph) {
            float4 e4[5], u0[5], u1[5], u2[5];
#pragma unroll
            for (int q = 0; q < 5; ++q) {
                int p4 = ph * 5 + q;
                e4[q] = row4[p4];
                u0[q] = *(const float4*)(uw + 4 * p4);
                u1[q] = *(const float4*)(uw + DEPC + 4 * p4);
                u2[q] = *(const float4*)(uw + 2 * DEPC + 4 * p4);
            }
#pragma unroll
            for (int q = 0; q < 5; ++q) {
                A0.x += e4[q].x * u0[q].x; A0.y += e4[q].y * u0[q].y;
                A0.z += e4[q].z * u0[q].z; A0.w += e4[q].w * u0[q].w;
                A1.x += e4[q].x * u1[q].x; A1.y += e4[q].y * u1[q].y;
                A1.z += e4[q].z * u1[q].z; A1.w += e4[q].w * u1[q].w;
                A2.x += e4[q].x * u2[q].x; A2.y += e4[q].y * u2[q].y;
                A2.z += e4[q].z * u2[q].z; A2.w += e4[q].w * u2[q].w;
            }
        }
        float a0 = (A0.x + A0.y) + (A0.z + A0.w);
        float a1 = (A1.x + A1.y) + (A1.z + A1.w);
        float a2 = (A2.x + A2.y) + (A2.z + A2.w);

        int j = c * 64 + lane;
        size_t sb = (((size_t)b * HH + hbase) * SS + i) * SS + j;
        scores[sb]                       = mk[c] ? fmaxf(a0, 0.f) : -1e6f;
        scores[sb + (size_t)SS * SS]     = mk[c] ? fmaxf(a1, 0.f) : -1e6f;
        scores[sb + 2 * (size_t)SS * SS] = mk[c] ? fmaxf(a2, 0.f) : -1e6f;
    }
}

// ---------- K4: softmax + ctx, 512 threads (j-range split across halves) ----------
#define GG 4
__global__ __launch_bounds__(512) void k_ctx(const float* __restrict__ scores,
                                             const float* __restrict__ V,
                                             const float* __restrict__ token,
                                             float* __restrict__ out) {
    __shared__ float sc[GG][HH][SS];  // 48 KB
    __shared__ float red[GG][DD];     // 12.3 KB partials
    int t = threadIdx.x, b = blockIdx.y, i0 = blockIdx.x * GG;
    for (int idx = t; idx < GG * HH * (SS / 4); idx += 512) {
        int jc = idx & 63, rr = idx >> 6;
        int g = rr / HH, h = rr % HH;
        float4 v = *(const float4*)(scores + (((size_t)b * HH + h) * SS + (i0 + g)) * SS + 4 * jc);
        *(float4*)&sc[g][h][4 * jc] = v;
    }
    __syncthreads();
    int lane = t & 63, w = t >> 6;  // 8 waves
    for (int rr = w; rr < GG * HH; rr += 8) {
        int g = rr / HH, h = rr % HH;
        float x0 = sc[g][h][lane],       x1 = sc[g][h][lane + 64];
        float x2 = sc[g][h][lane + 128], x3 = sc[g][h][lane + 192];
        float m = fmaxf(fmaxf(x0, x1), fmaxf(x2, x3));
#pragma unroll
        for (int o = 32; o > 0; o >>= 1) m = fmaxf(m, __shfl_xor(m, o, 64));
        x0 = __expf(x0 - m); x1 = __expf(x1 - m);
        x2 = __expf(x2 - m); x3 = __expf(x3 - m);
        float s = x0 + x1 + x2 + x3;
#pragma unroll
        for (int o = 32; o > 0; o >>= 1) s += __shfl_xor(s, o, 64);
        float inv = 1.0f / s;
        sc[g][h][lane] = x0 * inv;       sc[g][h][lane + 64] = x1 * inv;
        sc[g][h][lane + 128] = x2 * inv; sc[g][h][lane + 192] = x3 * inv;
    }
    __syncthreads();
    int half = t >> 8, tt = t & 255;
    float acc[3][GG] = {};
    for (int j0 = half * 128; j0 < half * 128 + 128; j0 += 4) {
#pragma unroll
        for (int a = 0; a < 3; ++a) {
            int hd = tt + 256 * a;
            int h = hd >> 6;
            float v0 = V[(size_t)(b * SS + j0) * DD + hd];
            float v1 = V[(size_t)(b * SS + j0 + 1) * DD + hd];
            float v2 = V[(size_t)(b * SS + j0 + 2) * DD + hd];
            float v3 = V[(size_t)(b * SS + j0 + 3) * DD + hd];
#pragma unroll
            for (int g = 0; g < GG; ++g) {
                float4 p = *(const float4*)&sc[g][h][j0];
                acc[a][g] += p.x * v0 + p.y * v1 + p.z * v2 + p.w * v3;
            }
        }
    }
    if (half == 1) {
#pragma unroll
        for (int a = 0; a < 3; ++a)
#pragma unroll
            for (int g = 0; g < GG; ++g) red[g][tt + 256 * a] = acc[a][g];
    }
    __syncthreads();
    if (half == 0) {
#pragma unroll
        for (int a = 0; a < 3; ++a) {
            int hd = tt + 256 * a;
#pragma unroll
            for (int g = 0; g < GG; ++g) {
                size_t o = (size_t)(b * SS + i0 + g) * DD + hd;
                out[o] = fmaxf(token[o] + acc[a][g] + red[g][hd], 0.f);
            }
        }
    }
}

extern "C" void kernel_launch(void* const* d_in, const int* in_sizes, int n_in,
                              void* d_out, int out_size, void* d_ws, size_t ws_size,
                              hipStream_t stream) {
    const float* token = (const float*)d_in[0];
    const float* edge  = (const float*)d_in[1];
    const int*   mask  = (const int*)d_in[2];
    const float* W_v   = (const float*)d_in[3];
    const float* W_e   = (const float*)d_in[4];
    const float* w_rel = (const float*)d_in[5];
    float* out = (float*)d_out;

    char* ws = (char*)d_ws;
    float* u_t    = (float*)(ws);                                   // 4.8 KB
    float* V      = (float*)(ws + 8192);                            // 3.15 MB
    float* scores = (float*)(ws + 8192 + (size_t)BB * SS * DD * 4); // 12.6 MB

    hipLaunchKernelGGL(k_u,   dim3((DEPC * HH + 255) / 256), dim3(256), 0, stream, W_e, w_rel, u_t);
    hipLaunchKernelGGL(k_v,   dim3((BB * SS) / TM, DD / TN), dim3(256), 0, stream, token, W_v, V);
    hipLaunchKernelGGL(k_sc,  dim3(SS, BB),                  dim3(256), 0, stream, edge, mask, u_t, scores);
    hipLaunchKernelGGL(k_ctx, dim3(SS / GG, BB),             dim3(512), 0, stream, scores, V, token, out);
}